// Round 6
// baseline (582.617 us; speedup 1.0000x reference)
//
#include <hip/hip_runtime.h>
#include <stdint.h>

#define N1 8192
#define N2 8192
#define DK 128
#define KF 256   // concat f16 K: [hi*64 | fp16(64*residual)]
#define BM 128
#define BN 128
#define BK 32
#define TAU 0.02f

typedef _Float16 half8 __attribute__((ext_vector_type(8)));
typedef _Float16 half4 __attribute__((ext_vector_type(4)));
typedef float floatx4 __attribute__((ext_vector_type(4)));

// Module-scope device scratch (graph-capture safe). All buffers fully
// rewritten every launch (re-poison safe).
__device__ __align__(16) _Float16 g_Af[N1 * KF];                      // 4 MB
__device__ __align__(16) _Float16 g_Bf[N2 * KF];                      // 4 MB
__device__ __align__(16) unsigned long long g_rowtop2[N1 * 128 * 2];  // 16 MB
__device__ __align__(16) unsigned long long g_coltop2[N2 * 128 * 2];  // 16 MB
__device__ int g_nn12[N1];
__device__ int g_nn21[N2];

__device__ __forceinline__ unsigned long long packmax(float v, unsigned idx) {
    unsigned u = __float_as_uint(v);
    u ^= (u & 0x80000000u) ? 0xFFFFFFFFu : 0x80000000u;
    return ((unsigned long long)u << 32) | (unsigned)(~idx);
}
__device__ __forceinline__ float unpackval(unsigned long long p) {
    unsigned key = (unsigned)(p >> 32);
    key ^= (key & 0x80000000u) ? 0x80000000u : 0xFFFFFFFFu;
    return __uint_as_float(key);
}
__device__ __forceinline__ unsigned long long umax64(unsigned long long a, unsigned long long b) {
    return a > b ? a : b;
}
__device__ __forceinline__ unsigned long long umin64(unsigned long long a, unsigned long long b) {
    return a < b ? a : b;
}
__device__ __forceinline__ unsigned long long shflx64(unsigned long long v, int m) {
    int lo = __shfl_xor((int)(v & 0xFFFFFFFFu), m, 64);
    int hi = __shfl_xor((int)(v >> 32), m, 64);
    return ((unsigned long long)(unsigned)hi << 32) | (unsigned)lo;
}
__device__ __forceinline__ void merge2(unsigned long long& t1, unsigned long long& t2,
                                       unsigned long long o1, unsigned long long o2) {
    unsigned long long n1 = umax64(t1, o1);
    unsigned long long n2 = umax64(umin64(t1, o1), umax64(t2, o2));
    t1 = n1; t2 = n2;
}
__device__ __forceinline__ void push2(unsigned long long& t1, unsigned long long& t2,
                                      unsigned long long p) {
    if (p > t1) { t2 = t1; t1 = p; } else if (p > t2) { t2 = p; }
}

__global__ __launch_bounds__(256) void convert_kernel(const float* __restrict__ A,
                                                      const float* __restrict__ B) {
    int t = blockIdx.x * blockDim.x + threadIdx.x;
    const int perMat = N1 * (DK / 4);
    int which = (t >= perMat) ? 1 : 0;
    const float* src = which ? B : A;
    _Float16* dst = which ? g_Bf : g_Af;
    int i = which ? t - perMat : t;
    int m = i >> 5;
    int kq = i & 31;
    float4 v = *reinterpret_cast<const float4*>(src + (size_t)m * DK + kq * 4);
    float vv[4] = {v.x, v.y, v.z, v.w};
    _Float16 hh[4], ll[4];
#pragma unroll
    for (int j = 0; j < 4; ++j) {
        _Float16 hj = (_Float16)vv[j];
        float r = (vv[j] - (float)hj) * 64.0f;
        hh[j] = (_Float16)((float)hj * 64.0f);
        ll[j] = (_Float16)r;
    }
    half4 h = {hh[0], hh[1], hh[2], hh[3]};
    half4 l = {ll[0], ll[1], ll[2], ll[3]};
    *reinterpret_cast<half4*>(dst + (size_t)m * KF + kq * 4) = h;
    *reinterpret_cast<half4*>(dst + (size_t)m * KF + DK + kq * 4) = l;
}

__global__ __launch_bounds__(256) void simf16_kernel() {
    __shared__ __align__(16) _Float16 As[BM * BK];
    __shared__ __align__(16) _Float16 Bs[BN * BK];

    const int tid  = threadIdx.x;
    const int lane = tid & 63;
    const int wave = tid >> 6;
    const int wm = wave >> 1;
    const int wn = wave & 1;
    const int row0 = blockIdx.y * BM;
    const int col0 = blockIdx.x * BN;

    floatx4 acc[4][4];
#pragma unroll
    for (int mt = 0; mt < 4; ++mt)
#pragma unroll
        for (int nt = 0; nt < 4; ++nt)
            acc[mt][nt] = (floatx4){0.f, 0.f, 0.f, 0.f};

    const int r_sl = lane >> 2;
    const int ch   = lane & 3;

    for (int k0 = 0; k0 < KF; k0 += BK) {
#pragma unroll
        for (int i = 0; i < 2; ++i) {
            int s = wave * 2 + i;
            const _Float16* gA = g_Af + (size_t)(row0 + s * 16 + r_sl) * KF + k0 + ch * 8;
            const _Float16* gB = g_Bf + (size_t)(col0 + s * 16 + r_sl) * KF + k0 + ch * 8;
            __builtin_amdgcn_global_load_lds(
                (const __attribute__((address_space(1))) void*)gA,
                (__attribute__((address_space(3))) void*)(As + s * 16 * BK), 16, 0, 0);
            __builtin_amdgcn_global_load_lds(
                (const __attribute__((address_space(1))) void*)gB,
                (__attribute__((address_space(3))) void*)(Bs + s * 16 * BK), 16, 0, 0);
        }
        __syncthreads();

        const int fr = lane & 15;
        const int q  = lane >> 4;
        half8 af[4], bf[4];
#pragma unroll
        for (int mt = 0; mt < 4; ++mt)
            af[mt] = *reinterpret_cast<const half8*>(As + (wm * 64 + mt * 16 + fr) * BK + q * 8);
#pragma unroll
        for (int nt = 0; nt < 4; ++nt)
            bf[nt] = *reinterpret_cast<const half8*>(Bs + (wn * 64 + nt * 16 + fr) * BK + q * 8);
#pragma unroll
        for (int mt = 0; mt < 4; ++mt)
#pragma unroll
            for (int nt = 0; nt < 4; ++nt)
                acc[mt][nt] = __builtin_amdgcn_mfma_f32_16x16x32_f16(af[mt], bf[nt], acc[mt][nt], 0, 0, 0);
        __syncthreads();
    }

    // ---- top-2 epilogue (C/D map: col=lane&15, row=(lane>>4)*4+reg) ----
    const float scale = 1.0f / 4096.0f;

#pragma unroll
    for (int mt = 0; mt < 4; ++mt) {
#pragma unroll
        for (int reg = 0; reg < 4; ++reg) {
            unsigned long long t1 = 0ULL, t2 = 0ULL;
#pragma unroll
            for (int nt = 0; nt < 4; ++nt) {
                unsigned n = col0 + wn * 64 + nt * 16 + (lane & 15);
                push2(t1, t2, packmax(acc[mt][nt][reg] * scale, n));
            }
#pragma unroll
            for (int off = 1; off < 16; off <<= 1) {
                unsigned long long o1 = shflx64(t1, off), o2 = shflx64(t2, off);
                merge2(t1, t2, o1, o2);
            }
            if ((lane & 15) == 0) {
                int m = row0 + wm * 64 + mt * 16 + (lane >> 4) * 4 + reg;
                int ht = blockIdx.x * 2 + wn;
                g_rowtop2[((size_t)m * 128 + ht) * 2 + 0] = t1;
                g_rowtop2[((size_t)m * 128 + ht) * 2 + 1] = t2;
            }
        }
    }
#pragma unroll
    for (int nt = 0; nt < 4; ++nt) {
        unsigned long long t1 = 0ULL, t2 = 0ULL;
#pragma unroll
        for (int mt = 0; mt < 4; ++mt)
#pragma unroll
            for (int reg = 0; reg < 4; ++reg) {
                unsigned m = row0 + wm * 64 + mt * 16 + (lane >> 4) * 4 + reg;
                push2(t1, t2, packmax(acc[mt][nt][reg] * scale, m));
            }
        {
            unsigned long long o1 = shflx64(t1, 16), o2 = shflx64(t2, 16);
            merge2(t1, t2, o1, o2);
            o1 = shflx64(t1, 32); o2 = shflx64(t2, 32);
            merge2(t1, t2, o1, o2);
        }
        if (lane < 16) {
            int n = col0 + wn * 64 + nt * 16 + lane;
            int ht = blockIdx.y * 2 + wm;
            g_coltop2[((size_t)n * 128 + ht) * 2 + 0] = t1;
            g_coltop2[((size_t)n * 128 + ht) * 2 + 1] = t2;
        }
    }
}

// One wave per row. Candidates within TAU of approx max are re-evaluated with
// an fp32 SEQUENTIAL k-ascending fmaf chain — bitwise-identical rounding to the
// numpy/OpenBLAS sgemm reference (single-accumulator k-ascending FMA), so
// near-ties resolve exactly as the reference does. All lanes compute the same
// dot (uniform addresses -> broadcast loads); strict FP order (no fast-math).
__global__ __launch_bounds__(256) void rowfix_kernel(const float* __restrict__ A,
                                                     const float* __restrict__ B,
                                                     float* __restrict__ out) {
    const int lane = threadIdx.x & 63;
    const int wave = threadIdx.x >> 6;
    const int r = blockIdx.x * 4 + wave;

    unsigned long long e[4];
    const unsigned long long* base = g_rowtop2 + (size_t)r * 256 + lane * 4;
#pragma unroll
    for (int j = 0; j < 4; ++j) e[j] = base[j];

    unsigned long long m = umax64(e[0], e[2]);
#pragma unroll
    for (int off = 1; off < 64; off <<= 1) m = umax64(m, shflx64(m, off));
    const float thr = unpackval(m) - TAU;

    unsigned mask = 0;
#pragma unroll
    for (int j = 0; j < 4; ++j)
        if (unpackval(e[j]) >= thr) mask |= 1u << j;

    float bestd = -1e30f;
    int bestc = 0x7FFFFFFF;
    while (true) {
        unsigned long long bal = __ballot(mask != 0);
        if (!bal) break;
        int src = __ffsll(bal) - 1;
        int myj = __ffs(mask) - 1;
        unsigned myc = (myj >= 0) ? ~(unsigned)e[myj & 3] : 0u;
        int c = __shfl((int)myc, src, 64);
        if (lane == src) mask &= mask - 1;
        float d = 0.0f;
#pragma unroll
        for (int k = 0; k < DK; ++k)
            d = fmaf(A[(size_t)r * DK + k], B[(size_t)c * DK + k], d);
        if (d > bestd || (d == bestd && c < bestc)) { bestd = d; bestc = c; }
    }
    if (lane == 0) {
        g_nn12[r] = bestc;
        out[N1 + r] = bestd;   // scores (float32, reference-identical rounding)
    }
}

__global__ __launch_bounds__(256) void colfix_kernel(const float* __restrict__ A,
                                                     const float* __restrict__ B) {
    const int lane = threadIdx.x & 63;
    const int wave = threadIdx.x >> 6;
    const int c = blockIdx.x * 4 + wave;

    unsigned long long e[4];
    const unsigned long long* base = g_coltop2 + (size_t)c * 256 + lane * 4;
#pragma unroll
    for (int j = 0; j < 4; ++j) e[j] = base[j];

    unsigned long long m = umax64(e[0], e[2]);
#pragma unroll
    for (int off = 1; off < 64; off <<= 1) m = umax64(m, shflx64(m, off));
    const float thr = unpackval(m) - TAU;

    unsigned mask = 0;
#pragma unroll
    for (int j = 0; j < 4; ++j)
        if (unpackval(e[j]) >= thr) mask |= 1u << j;

    float bestd = -1e30f;
    int bestr = 0x7FFFFFFF;
    while (true) {
        unsigned long long bal = __ballot(mask != 0);
        if (!bal) break;
        int src = __ffsll(bal) - 1;
        int myj = __ffs(mask) - 1;
        unsigned myr = (myj >= 0) ? ~(unsigned)e[myj & 3] : 0u;
        int rr = __shfl((int)myr, src, 64);
        if (lane == src) mask &= mask - 1;
        float d = 0.0f;
#pragma unroll
        for (int k = 0; k < DK; ++k)
            d = fmaf(A[(size_t)rr * DK + k], B[(size_t)c * DK + k], d);
        if (d > bestd || (d == bestd && rr < bestr)) { bestd = d; bestr = rr; }
    }
    if (lane == 0) g_nn21[c] = bestr;
}

__global__ void mutual_kernel(float* __restrict__ out) {
    int i = blockIdx.x * blockDim.x + threadIdx.x;
    if (i < N1) {
        int m = g_nn12[i];
        int v = (g_nn21[m] == i) ? m : -1;
        out[i] = (float)v;   // matches0 (float32)
    }
}

extern "C" void kernel_launch(void* const* d_in, const int* in_sizes, int n_in,
                              void* d_out, int out_size, void* d_ws, size_t ws_size,
                              hipStream_t stream) {
    const float* A = (const float*)d_in[0];   // desc1 [8192,128] f32
    const float* B = (const float*)d_in[1];   // desc2 [8192,128] f32
    float* out = (float*)d_out;               // [0:8192]=matches, [8192:16384]=scores

    convert_kernel<<<2 * N1 * (DK / 4) / 256, 256, 0, stream>>>(A, B);
    dim3 grid(N2 / BN, N1 / BM);
    simf16_kernel<<<grid, 256, 0, stream>>>();
    rowfix_kernel<<<N1 / 4, 256, 0, stream>>>(A, B, out);
    colfix_kernel<<<N2 / 4, 256, 0, stream>>>(A, B);
    mutual_kernel<<<(N1 + 255) / 256, 256, 0, stream>>>(out);
}

// Round 7
// 225.426 us; speedup vs baseline: 2.5845x; 2.5845x over previous
//
#include <hip/hip_runtime.h>
#include <stdint.h>

#define N1 8192
#define N2 8192
#define DK 128
#define KF 256            // concat f16 K: [hi*64 | fp16(64*residual)]
#define TAU_RAW (0.02f * 4096.0f)   // repair margin in raw (4096x) units

typedef _Float16 half8 __attribute__((ext_vector_type(8)));
typedef _Float16 half4 __attribute__((ext_vector_type(4)));
typedef float floatx4 __attribute__((ext_vector_type(4)));

// Module-scope device scratch (graph-capture safe). Fully rewritten each launch.
__device__ __align__(16) _Float16 g_Af[N1 * KF];        // 4 MB
__device__ __align__(16) _Float16 g_Bf[N2 * KF];        // 4 MB
__device__ __align__(16) uint2 g_rowtop2[64 * N1];      // 4 MB [colgrp][row] block-owned
__device__ __align__(16) uint2 g_coltop2[64 * N2];      // 4 MB [rowgrp][col]
__device__ int g_nn12[N1];
__device__ int g_nn21[N2];

// order-preserving f32 -> u32
__device__ __forceinline__ unsigned mono32(float v) {
    unsigned u = __float_as_uint(v);
    return u ^ ((u & 0x80000000u) ? 0xFFFFFFFFu : 0x80000000u);
}
__device__ __forceinline__ float unmono32(unsigned k) {
    unsigned u = (k & 0x80000000u) ? (k ^ 0x80000000u) : ~k;
    return __uint_as_float(u);
}
// quantized key: value's monotone bits with low 7 bits replaced by idx-in-group
__device__ __forceinline__ unsigned qkey(float v, unsigned idx7) {
    return (mono32(v) & 0xFFFFFF80u) | idx7;
}
__device__ __forceinline__ void push2u(unsigned& t1, unsigned& t2, unsigned p) {
    unsigned lo = min(t1, p);
    t1 = max(t1, p);
    t2 = max(t2, lo);
}
__device__ __forceinline__ void merge2u(unsigned& t1, unsigned& t2, unsigned o1, unsigned o2) {
    unsigned n1 = max(t1, o1);
    unsigned n2 = max(min(t1, o1), max(t2, o2));
    t1 = n1; t2 = n2;
}

// fp32 -> f16 split (H=64*fp16(x), L=fp16(64*(x-fp16(x)))), concat along K.
__global__ __launch_bounds__(256) void convert_kernel(const float* __restrict__ A,
                                                      const float* __restrict__ B) {
    int t = blockIdx.x * blockDim.x + threadIdx.x;
    const int perMat = N1 * (DK / 4);
    int which = (t >= perMat) ? 1 : 0;
    const float* src = which ? B : A;
    _Float16* dst = which ? g_Bf : g_Af;
    int i = which ? t - perMat : t;
    int m = i >> 5;
    int kq = i & 31;
    float4 v = *reinterpret_cast<const float4*>(src + (size_t)m * DK + kq * 4);
    float vv[4] = {v.x, v.y, v.z, v.w};
    _Float16 hh[4], ll[4];
#pragma unroll
    for (int j = 0; j < 4; ++j) {
        _Float16 hj = (_Float16)vv[j];
        float r = (vv[j] - (float)hj) * 64.0f;
        hh[j] = (_Float16)((float)hj * 64.0f);
        ll[j] = (_Float16)r;
    }
    half4 h = {hh[0], hh[1], hh[2], hh[3]};
    half4 l = {ll[0], ll[1], ll[2], ll[3]};
    *reinterpret_cast<half4*>(dst + (size_t)m * KF + kq * 4) = h;
    *reinterpret_cast<half4*>(dst + (size_t)m * KF + DK + kq * 4) = l;
}

// 128x128 tile per block, 4 waves, NO LDS staging / NO K-loop barriers:
// MFMA fragments loaded directly from global (L2-resident, 8 MB total).
__global__ __launch_bounds__(256) void simf16_kernel() {
    __shared__ uint2 lmerge[2][128];   // 2 KB, epilogue cross-wave merge

    const int tid  = threadIdx.x;
    const int lane = tid & 63;
    const int wave = tid >> 6;
    const int wm = wave >> 1, wn = wave & 1;
    const int row0 = blockIdx.y * 128, col0 = blockIdx.x * 128;
    const int fr = lane & 15, q = lane >> 4;

    floatx4 acc[4][4];
#pragma unroll
    for (int mt = 0; mt < 4; ++mt)
#pragma unroll
        for (int nt = 0; nt < 4; ++nt)
            acc[mt][nt] = (floatx4){0.f, 0.f, 0.f, 0.f};

    const _Float16* Ab = g_Af + (size_t)(row0 + wm * 64 + fr) * KF + q * 8;
    const _Float16* Bb = g_Bf + (size_t)(col0 + wn * 64 + fr) * KF + q * 8;

#pragma unroll
    for (int ks = 0; ks < 8; ++ks) {
        half8 af[4], bf[4];
#pragma unroll
        for (int mt = 0; mt < 4; ++mt)
            af[mt] = *reinterpret_cast<const half8*>(Ab + mt * 16 * KF + ks * 32);
#pragma unroll
        for (int nt = 0; nt < 4; ++nt)
            bf[nt] = *reinterpret_cast<const half8*>(Bb + nt * 16 * KF + ks * 32);
#pragma unroll
        for (int mt = 0; mt < 4; ++mt)
#pragma unroll
            for (int nt = 0; nt < 4; ++nt)
                acc[mt][nt] = __builtin_amdgcn_mfma_f32_16x16x32_f16(af[mt], bf[nt], acc[mt][nt], 0, 0, 0);
    }

    // ---- row phase: top2 over this block's 128 cols (C/D: col=lane&15, row=q*4+reg) ----
#pragma unroll
    for (int mt = 0; mt < 4; ++mt) {
#pragma unroll
        for (int reg = 0; reg < 4; ++reg) {
            unsigned t1 = 0u, t2 = 0u;
#pragma unroll
            for (int nt = 0; nt < 4; ++nt)
                push2u(t1, t2, qkey(acc[mt][nt][reg], (unsigned)(wn * 64 + nt * 16 + fr)));
#pragma unroll
            for (int off = 1; off < 16; off <<= 1) {
                unsigned o1 = __shfl_xor(t1, off, 64);
                unsigned o2 = __shfl_xor(t2, off, 64);
                merge2u(t1, t2, o1, o2);
            }
            if (fr == 0) lmerge[wn][wm * 64 + mt * 16 + q * 4 + reg] = make_uint2(t1, t2);
        }
    }
    __syncthreads();
    if (tid < 128) {
        uint2 a = lmerge[0][tid], b = lmerge[1][tid];
        merge2u(a.x, a.y, b.x, b.y);
        g_rowtop2[(size_t)blockIdx.x * N1 + row0 + tid] = a;   // contiguous 1 KB/block
    }
    __syncthreads();

    // ---- col phase: top2 over this block's 128 rows ----
#pragma unroll
    for (int nt = 0; nt < 4; ++nt) {
        unsigned t1 = 0u, t2 = 0u;
#pragma unroll
        for (int mt = 0; mt < 4; ++mt)
#pragma unroll
            for (int reg = 0; reg < 4; ++reg)
                push2u(t1, t2, qkey(acc[mt][nt][reg], (unsigned)(wm * 64 + mt * 16 + q * 4 + reg)));
        unsigned o1 = __shfl_xor(t1, 16, 64), o2 = __shfl_xor(t2, 16, 64);
        merge2u(t1, t2, o1, o2);
        o1 = __shfl_xor(t1, 32, 64); o2 = __shfl_xor(t2, 32, 64);
        merge2u(t1, t2, o1, o2);
        if (q == 0) lmerge[wm][wn * 64 + nt * 16 + fr] = make_uint2(t1, t2);
    }
    __syncthreads();
    if (tid < 128) {
        uint2 a = lmerge[0][tid], b = lmerge[1][tid];
        merge2u(a.x, a.y, b.x, b.y);
        g_coltop2[(size_t)blockIdx.y * N2 + col0 + tid] = a;
    }
}

// One wave per row: candidates within TAU of approx max re-evaluated with the
// fp32 SEQUENTIAL k-ascending fmaf chain (bitwise-identical to the np reference
// rounding — R6-proven). Exact argmax + exact score written.
__global__ __launch_bounds__(256) void rowfix_kernel(const float* __restrict__ A,
                                                     const float* __restrict__ B,
                                                     float* __restrict__ out) {
    const int lane = threadIdx.x & 63;
    const int wave = threadIdx.x >> 6;
    const int r = blockIdx.x * 4 + wave;

    uint2 e = g_rowtop2[(size_t)lane * N1 + r];
    float v1 = unmono32(e.x & 0xFFFFFF80u);
    float v2 = unmono32(e.y & 0xFFFFFF80u);
    float mx = v1;
#pragma unroll
    for (int off = 1; off < 64; off <<= 1)
        mx = fmaxf(mx, __shfl_xor(mx, off, 64));
    const float thr = mx - TAU_RAW - 16.0f;   // 16 raw = quantization slack
    unsigned mask = (v1 >= thr ? 1u : 0u) | (v2 >= thr ? 2u : 0u);

    float bestd = -1e30f;
    int bestc = 0x7FFFFFFF;
    while (true) {
        unsigned long long bal = __ballot(mask != 0);
        if (!bal) break;
        int src = __ffsll((unsigned long long)bal) - 1;
        int myj = __ffs((int)mask) - 1;
        unsigned key = (myj == 0) ? e.x : e.y;
        int c = lane * 128 + (int)(key & 127u);
        c = __shfl(c, src, 64);
        if (lane == src) mask &= mask - 1;
        float d = 0.0f;
#pragma unroll
        for (int k = 0; k < DK; ++k)
            d = fmaf(A[(size_t)r * DK + k], B[(size_t)c * DK + k], d);
        if (d > bestd || (d == bestd && c < bestc)) { bestd = d; bestc = c; }
    }
    if (lane == 0) {
        g_nn12[r] = bestc;
        out[N1 + r] = bestd;   // scores (reference-identical rounding)
    }
}

__global__ __launch_bounds__(256) void colfix_kernel(const float* __restrict__ A,
                                                     const float* __restrict__ B) {
    const int lane = threadIdx.x & 63;
    const int wave = threadIdx.x >> 6;
    const int c = blockIdx.x * 4 + wave;

    uint2 e = g_coltop2[(size_t)lane * N2 + c];
    float v1 = unmono32(e.x & 0xFFFFFF80u);
    float v2 = unmono32(e.y & 0xFFFFFF80u);
    float mx = v1;
#pragma unroll
    for (int off = 1; off < 64; off <<= 1)
        mx = fmaxf(mx, __shfl_xor(mx, off, 64));
    const float thr = mx - TAU_RAW - 16.0f;
    unsigned mask = (v1 >= thr ? 1u : 0u) | (v2 >= thr ? 2u : 0u);

    float bestd = -1e30f;
    int bestr = 0x7FFFFFFF;
    while (true) {
        unsigned long long bal = __ballot(mask != 0);
        if (!bal) break;
        int src = __ffsll((unsigned long long)bal) - 1;
        int myj = __ffs((int)mask) - 1;
        unsigned key = (myj == 0) ? e.x : e.y;
        int rr = lane * 128 + (int)(key & 127u);
        rr = __shfl(rr, src, 64);
        if (lane == src) mask &= mask - 1;
        float d = 0.0f;
#pragma unroll
        for (int k = 0; k < DK; ++k)
            d = fmaf(A[(size_t)rr * DK + k], B[(size_t)c * DK + k], d);
        if (d > bestd || (d == bestd && rr < bestr)) { bestd = d; bestr = rr; }
    }
    if (lane == 0) g_nn21[c] = bestr;
}

__global__ void mutual_kernel(float* __restrict__ out) {
    int i = blockIdx.x * blockDim.x + threadIdx.x;
    if (i < N1) {
        int m = g_nn12[i];
        int v = (g_nn21[m] == i) ? m : -1;
        out[i] = (float)v;   // matches0
    }
}

extern "C" void kernel_launch(void* const* d_in, const int* in_sizes, int n_in,
                              void* d_out, int out_size, void* d_ws, size_t ws_size,
                              hipStream_t stream) {
    const float* A = (const float*)d_in[0];   // desc1 [8192,128] f32
    const float* B = (const float*)d_in[1];   // desc2 [8192,128] f32
    float* out = (float*)d_out;               // [0:8192]=matches, [8192:16384]=scores

    convert_kernel<<<2 * N1 * (DK / 4) / 256, 256, 0, stream>>>(A, B);
    dim3 grid(N2 / 128, N1 / 128);
    simf16_kernel<<<grid, 256, 0, stream>>>();
    rowfix_kernel<<<N1 / 4, 256, 0, stream>>>(A, B, out);
    colfix_kernel<<<N2 / 4, 256, 0, stream>>>(A, B);
    mutual_kernel<<<(N1 + 255) / 256, 256, 0, stream>>>(out);
}

// Round 8
// 145.259 us; speedup vs baseline: 4.0109x; 1.5519x over previous
//
#include <hip/hip_runtime.h>
#include <stdint.h>

#define N1 8192
#define N2 8192
#define DK 128
#define TAU 0.08f     // repair margin (sim units); ~15 sigma of single-f16 dot noise

typedef _Float16 half8 __attribute__((ext_vector_type(8)));
typedef _Float16 half4 __attribute__((ext_vector_type(4)));
typedef float floatx4 __attribute__((ext_vector_type(4)));

// Module-scope device scratch (graph-capture safe). Fully rewritten each launch.
__device__ __align__(16) _Float16 g_Af[N1 * DK];        // 2 MB
__device__ __align__(16) _Float16 g_Bf[N2 * DK];        // 2 MB
__device__ __align__(16) uint2 g_rowtop2[64 * N1];      // 4 MB [colgrp][row] block-owned runs
__device__ __align__(16) uint2 g_coltop2[64 * N2];      // 4 MB [rowgrp][col]
__device__ int g_nn12[N1];
__device__ int g_nn21[N2];

// order-preserving f32 <-> u32
__device__ __forceinline__ unsigned mono32(float v) {
    unsigned u = __float_as_uint(v);
    return u ^ ((u & 0x80000000u) ? 0xFFFFFFFFu : 0x80000000u);
}
__device__ __forceinline__ float unmono32(unsigned k) {
    unsigned u = (k & 0x80000000u) ? (k ^ 0x80000000u) : ~k;
    return __uint_as_float(u);
}
// key: monotone value bits, low 7 bits = idx within 128-group (quant ~5e-4 << TAU)
__device__ __forceinline__ unsigned qkey(float v, unsigned idx7) {
    return (mono32(v) & 0xFFFFFF80u) | idx7;
}
__device__ __forceinline__ void push2u(unsigned& t1, unsigned& t2, unsigned p) {
    unsigned lo = min(t1, p);
    t1 = max(t1, p);
    t2 = max(t2, lo);
}
__device__ __forceinline__ void merge2u(unsigned& t1, unsigned& t2, unsigned o1, unsigned o2) {
    unsigned n1 = max(t1, o1);
    unsigned n2 = max(min(t1, o1), max(t2, o2));
    t1 = n1; t2 = n2;
}
__device__ __forceinline__ unsigned long long pack64(float d, unsigned idx) {
    return ((unsigned long long)mono32(d) << 32) | (unsigned)(~idx);
}

// fp32 -> f16 direct (single precision level; repair pass handles near-ties).
__global__ __launch_bounds__(256) void convert_kernel(const float* __restrict__ A,
                                                      const float* __restrict__ B) {
    int t = blockIdx.x * blockDim.x + threadIdx.x;
    const int perMat = N1 * (DK / 4);
    int which = (t >= perMat) ? 1 : 0;
    const float* src = which ? B : A;
    _Float16* dst = which ? g_Bf : g_Af;
    int i = which ? t - perMat : t;
    int m = i >> 5;
    int kq = i & 31;
    float4 v = *reinterpret_cast<const float4*>(src + (size_t)m * DK + kq * 4);
    half4 h = {(_Float16)v.x, (_Float16)v.y, (_Float16)v.z, (_Float16)v.w};
    *reinterpret_cast<half4*>(dst + (size_t)m * DK + kq * 4) = h;
}

// 128x128 tile per block, 4 waves, no LDS staging, no K-loop barriers.
// Whole f16 problem = 4 MB -> fits each XCD's L2.
__global__ __launch_bounds__(256) void simf16_kernel() {
    __shared__ uint2 lmerge[2][128];

    const int tid  = threadIdx.x;
    const int lane = tid & 63;
    const int wave = tid >> 6;
    const int wm = wave >> 1, wn = wave & 1;
    const int row0 = blockIdx.y * 128, col0 = blockIdx.x * 128;
    const int fr = lane & 15, q = lane >> 4;

    floatx4 acc[4][4];
#pragma unroll
    for (int mt = 0; mt < 4; ++mt)
#pragma unroll
        for (int nt = 0; nt < 4; ++nt)
            acc[mt][nt] = (floatx4){0.f, 0.f, 0.f, 0.f};

    const _Float16* Ab = g_Af + (size_t)(row0 + wm * 64 + fr) * DK + q * 8;
    const _Float16* Bb = g_Bf + (size_t)(col0 + wn * 64 + fr) * DK + q * 8;

#pragma unroll
    for (int ks = 0; ks < 4; ++ks) {
        half8 af[4], bf[4];
#pragma unroll
        for (int mt = 0; mt < 4; ++mt)
            af[mt] = *reinterpret_cast<const half8*>(Ab + mt * 16 * DK + ks * 32);
#pragma unroll
        for (int nt = 0; nt < 4; ++nt)
            bf[nt] = *reinterpret_cast<const half8*>(Bb + nt * 16 * DK + ks * 32);
#pragma unroll
        for (int mt = 0; mt < 4; ++mt)
#pragma unroll
            for (int nt = 0; nt < 4; ++nt)
                acc[mt][nt] = __builtin_amdgcn_mfma_f32_16x16x32_f16(af[mt], bf[nt], acc[mt][nt], 0, 0, 0);
    }

    // ---- row phase: top2 over 128 cols (C/D: col=lane&15, row=q*4+reg) ----
#pragma unroll
    for (int mt = 0; mt < 4; ++mt) {
#pragma unroll
        for (int reg = 0; reg < 4; ++reg) {
            unsigned t1 = 0u, t2 = 0u;
#pragma unroll
            for (int nt = 0; nt < 4; ++nt)
                push2u(t1, t2, qkey(acc[mt][nt][reg], (unsigned)(wn * 64 + nt * 16 + fr)));
#pragma unroll
            for (int off = 1; off < 16; off <<= 1) {
                unsigned o1 = __shfl_xor(t1, off, 64);
                unsigned o2 = __shfl_xor(t2, off, 64);
                merge2u(t1, t2, o1, o2);
            }
            if (fr == 0) lmerge[wn][wm * 64 + mt * 16 + q * 4 + reg] = make_uint2(t1, t2);
        }
    }
    __syncthreads();
    if (tid < 128) {
        uint2 a = lmerge[0][tid], b = lmerge[1][tid];
        merge2u(a.x, a.y, b.x, b.y);
        g_rowtop2[(size_t)blockIdx.x * N1 + row0 + tid] = a;   // contiguous 1 KB run
    }
    __syncthreads();

    // ---- col phase: top2 over 128 rows ----
#pragma unroll
    for (int nt = 0; nt < 4; ++nt) {
        unsigned t1 = 0u, t2 = 0u;
#pragma unroll
        for (int mt = 0; mt < 4; ++mt)
#pragma unroll
            for (int reg = 0; reg < 4; ++reg)
                push2u(t1, t2, qkey(acc[mt][nt][reg], (unsigned)(wm * 64 + mt * 16 + q * 4 + reg)));
        unsigned o1 = __shfl_xor(t1, 16, 64), o2 = __shfl_xor(t2, 16, 64);
        merge2u(t1, t2, o1, o2);
        o1 = __shfl_xor(t1, 32, 64); o2 = __shfl_xor(t2, 32, 64);
        merge2u(t1, t2, o1, o2);
        if (q == 0) lmerge[wm][wn * 64 + nt * 16 + fr] = make_uint2(t1, t2);
    }
    __syncthreads();
    if (tid < 128) {
        uint2 a = lmerge[0][tid], b = lmerge[1][tid];
        merge2u(a.x, a.y, b.x, b.y);
        g_coltop2[(size_t)blockIdx.y * N2 + col0 + tid] = a;
    }
}

// 64 rows per block. Coalesced LDS staging of the [grp][row] top2 runs, per-row
// approx max, candidates within TAU re-evaluated with the fp32 SEQUENTIAL
// k-ascending fmaf chain (bitwise reference rounding, R6-proven), per-row LDS
// u64 atomicMax (tie -> smaller index via ~idx).
__global__ __launch_bounds__(256) void rowfix_kernel(const float* __restrict__ A,
                                                     const float* __restrict__ B,
                                                     float* __restrict__ out) {
    __shared__ uint2 tile[64 * 64];              // 32 KB
    __shared__ unsigned long long slot[64];
    __shared__ float rowmx[64];
    __shared__ int cand_cnt;
    __shared__ int cand[512];

    const int tid = threadIdx.x;
    const int r0 = blockIdx.x * 64;

#pragma unroll
    for (int i = 0; i < 16; ++i) {
        int idx = i * 256 + tid;                 // 0..4095
        int grp = idx >> 6, row = idx & 63;
        tile[grp * 64 + row] = g_rowtop2[(size_t)grp * N1 + r0 + row];
    }
    if (tid == 0) cand_cnt = 0;
    if (tid < 64) slot[tid] = 0ULL;
    __syncthreads();

    const int row = tid >> 2, j = tid & 3;
    float mx = -1e30f;
#pragma unroll
    for (int s = 0; s < 16; ++s) {
        uint2 e = tile[(j * 16 + s) * 64 + row];
        mx = fmaxf(mx, unmono32(e.x & 0xFFFFFF80u));
    }
    mx = fmaxf(mx, __shfl_xor(mx, 1, 64));
    mx = fmaxf(mx, __shfl_xor(mx, 2, 64));
    if (j == 0) rowmx[row] = mx;
    __syncthreads();

    const float thr = rowmx[row] - TAU;
#pragma unroll
    for (int s = 0; s < 16; ++s) {
        int grp = j * 16 + s;
        uint2 e = tile[grp * 64 + row];
        if (unmono32(e.x & 0xFFFFFF80u) >= thr) {
            int c = grp * 128 + (int)(e.x & 127u);
            int si = atomicAdd(&cand_cnt, 1);
            if (si < 512) cand[si] = (row << 16) | c;
        }
        if (unmono32(e.y & 0xFFFFFF80u) >= thr) {
            int c = grp * 128 + (int)(e.y & 127u);
            int si = atomicAdd(&cand_cnt, 1);
            if (si < 512) cand[si] = (row << 16) | c;
        }
    }
    __syncthreads();

    const int nc = min(cand_cnt, 512);
    for (int i = tid; i < nc; i += 256) {
        int pc = cand[i];
        int rw = pc >> 16, c = pc & 0xFFFF;
        const float* ar = A + (size_t)(r0 + rw) * DK;
        const float* br = B + (size_t)c * DK;
        float d = 0.0f;
#pragma unroll
        for (int k4 = 0; k4 < DK / 4; ++k4) {
            float4 a = *reinterpret_cast<const float4*>(ar + k4 * 4);
            float4 b = *reinterpret_cast<const float4*>(br + k4 * 4);
            d = fmaf(a.x, b.x, d);
            d = fmaf(a.y, b.y, d);
            d = fmaf(a.z, b.z, d);
            d = fmaf(a.w, b.w, d);
        }
        atomicMax(&slot[rw], pack64(d, (unsigned)c));
    }
    __syncthreads();

    if (tid < 64) {
        unsigned long long p = slot[tid];
        g_nn12[r0 + tid] = (int)(~(unsigned)p);
        unsigned key = (unsigned)(p >> 32);
        out[N1 + r0 + tid] = unmono32(key);      // exact score, reference rounding
    }
}

__global__ __launch_bounds__(256) void colfix_kernel(const float* __restrict__ A,
                                                     const float* __restrict__ B) {
    __shared__ uint2 tile[64 * 64];
    __shared__ unsigned long long slot[64];
    __shared__ float colmx[64];
    __shared__ int cand_cnt;
    __shared__ int cand[512];

    const int tid = threadIdx.x;
    const int c0 = blockIdx.x * 64;

#pragma unroll
    for (int i = 0; i < 16; ++i) {
        int idx = i * 256 + tid;
        int grp = idx >> 6, col = idx & 63;
        tile[grp * 64 + col] = g_coltop2[(size_t)grp * N2 + c0 + col];
    }
    if (tid == 0) cand_cnt = 0;
    if (tid < 64) slot[tid] = 0ULL;
    __syncthreads();

    const int col = tid >> 2, j = tid & 3;
    float mx = -1e30f;
#pragma unroll
    for (int s = 0; s < 16; ++s) {
        uint2 e = tile[(j * 16 + s) * 64 + col];
        mx = fmaxf(mx, unmono32(e.x & 0xFFFFFF80u));
    }
    mx = fmaxf(mx, __shfl_xor(mx, 1, 64));
    mx = fmaxf(mx, __shfl_xor(mx, 2, 64));
    if (j == 0) colmx[col] = mx;
    __syncthreads();

    const float thr = colmx[col] - TAU;
#pragma unroll
    for (int s = 0; s < 16; ++s) {
        int grp = j * 16 + s;
        uint2 e = tile[grp * 64 + col];
        if (unmono32(e.x & 0xFFFFFF80u) >= thr) {
            int rr = grp * 128 + (int)(e.x & 127u);
            int si = atomicAdd(&cand_cnt, 1);
            if (si < 512) cand[si] = (col << 16) | rr;
        }
        if (unmono32(e.y & 0xFFFFFF80u) >= thr) {
            int rr = grp * 128 + (int)(e.y & 127u);
            int si = atomicAdd(&cand_cnt, 1);
            if (si < 512) cand[si] = (col << 16) | rr;
        }
    }
    __syncthreads();

    const int nc = min(cand_cnt, 512);
    for (int i = tid; i < nc; i += 256) {
        int pc = cand[i];
        int cl = pc >> 16, rr = pc & 0xFFFF;
        const float* ar = A + (size_t)rr * DK;
        const float* br = B + (size_t)(c0 + cl) * DK;
        float d = 0.0f;
#pragma unroll
        for (int k4 = 0; k4 < DK / 4; ++k4) {
            float4 a = *reinterpret_cast<const float4*>(ar + k4 * 4);
            float4 b = *reinterpret_cast<const float4*>(br + k4 * 4);
            d = fmaf(a.x, b.x, d);
            d = fmaf(a.y, b.y, d);
            d = fmaf(a.z, b.z, d);
            d = fmaf(a.w, b.w, d);
        }
        atomicMax(&slot[cl], pack64(d, (unsigned)rr));
    }
    __syncthreads();

    if (tid < 64) g_nn21[c0 + tid] = (int)(~(unsigned)slot[tid]);
}

__global__ void mutual_kernel(float* __restrict__ out) {
    int i = blockIdx.x * blockDim.x + threadIdx.x;
    if (i < N1) {
        int m = g_nn12[i];
        int v = (g_nn21[m] == i) ? m : -1;
        out[i] = (float)v;   // matches0
    }
}

extern "C" void kernel_launch(void* const* d_in, const int* in_sizes, int n_in,
                              void* d_out, int out_size, void* d_ws, size_t ws_size,
                              hipStream_t stream) {
    const float* A = (const float*)d_in[0];   // desc1 [8192,128] f32
    const float* B = (const float*)d_in[1];   // desc2 [8192,128] f32
    float* out = (float*)d_out;               // [0:8192]=matches, [8192:16384]=scores

    convert_kernel<<<2 * N1 * (DK / 4) / 256, 256, 0, stream>>>(A, B);
    dim3 grid(N2 / 128, N1 / 128);
    simf16_kernel<<<grid, 256, 0, stream>>>();
    rowfix_kernel<<<N1 / 64, 256, 0, stream>>>(A, B, out);
    colfix_kernel<<<N2 / 64, 256, 0, stream>>>(A, B);
    mutual_kernel<<<(N1 + 255) / 256, 256, 0, stream>>>(out);
}